// Round 3
// baseline (17.123 us; speedup 1.0000x reference)
//
#include <hip/hip_runtime.h>
#include <math.h>

#define HID 64
#define CHUNKS 8
#define NTHREADS 1024
#define NWAVES (NTHREADS / 64)

__global__ __launch_bounds__(NTHREADS) void spatial_attn_fused(
    const float* __restrict__ x,   // [B, N] flat
    const float* __restrict__ Wq, const float* __restrict__ bq,
    const float* __restrict__ Wk, const float* __restrict__ bk,
    const float* __restrict__ Wv, const float* __restrict__ bv,
    const float* __restrict__ Wo, const float* __restrict__ bo,
    float* __restrict__ out,       // [B, N] flat
    int N)
{
    // bid = b + 64*chunk  ->  all CHUNKS blocks of one batch land on the same
    // XCD (64 % 8 == 0), so their redundant pass-1 reads share one L2.
    const int bid   = blockIdx.x;
    const int b     = bid & 63;
    const int chunk = bid >> 6;
    const int tid   = threadIdx.x;
    const int wave  = tid >> 6, lane = tid & 63;
    const float* xb = x   + (size_t)b * N;
    float*       yb = out + (size_t)b * N;

    // Per-lane weight loads issued early (tiny, L2-hot after first block).
    const float wk_g = Wk[lane], bk_g = bk[lane];
    const float wv_g = Wv[lane], bv_g = bv[lane];

    // ---------------- Pass 1 (redundant per chunk): S1 = Σx, S2 = Σx² ------
    float s1 = 0.f, s2 = 0.f;
    const int nvec = N >> 2;                       // 7396 -> 1849 float4s
    const float4* xv = reinterpret_cast<const float4*>(xb);
    for (int i = tid; i < nvec; i += NTHREADS) {
        float4 v = xv[i];
        s1 += (v.x + v.y) + (v.z + v.w);
        s2 += v.x * v.x + v.y * v.y + v.z * v.z + v.w * v.w;
    }
    for (int i = (nvec << 2) + tid; i < N; i += NTHREADS) {  // tail (none for 7396)
        float v = xb[i];
        s1 += v; s2 += v * v;
    }
    #pragma unroll
    for (int off = 32; off > 0; off >>= 1) {
        s1 += __shfl_down(s1, off);
        s2 += __shfl_down(s2, off);
    }
    __shared__ float lds1[NWAVES], lds2[NWAVES], ldsA[NWAVES], ldsB[NWAVES];
    __shared__ float sS1, sS2, sAlpha, sBeta;
    if (lane == 0) { lds1[wave] = s1; lds2[wave] = s2; }
    __syncthreads();
    if (wave == 0) {                       // parallel 16-entry reduce on wave 0
        float a = (lane < NWAVES) ? lds1[lane] : 0.f;
        float c = (lane < NWAVES) ? lds2[lane] : 0.f;
        #pragma unroll
        for (int off = 8; off > 0; off >>= 1) {
            a += __shfl_down(a, off);
            c += __shfl_down(c, off);
        }
        if (lane == 0) { sS1 = a; sS2 = c; }
    }
    __syncthreads();
    const float S1 = sS1, S2 = sS2;

    // ---------------- Softmax, wave-parallel: wave w owns heads 4w..4w+3 ---
    // sc[h][g] = P_h * wk_g + Q_h * bk_g   (rank-2 score matrix, C==1)
    const float scale = 0.125f;           // 1/sqrt(64)
    const float fN = (float)N;
    float cA = 0.f, cB = 0.f;
    #pragma unroll
    for (int j = 0; j < HID / NWAVES; ++j) {   // 4 heads per wave
        const int h = wave * (HID / NWAVES) + j;
        const float wqh = Wq[h], bqh = bq[h];  // wave-uniform loads
        const float P = (wqh * S2 + bqh * S1) * scale;
        const float Q = (wqh * S1 + bqh * fN) * scale;
        const float sc = P * wk_g + Q * bk_g;
        float m = sc;
        #pragma unroll
        for (int off = 32; off > 0; off >>= 1) m = fmaxf(m, __shfl_xor(m, off));
        const float e = __expf(sc - m);
        float s = e, sA = e * wv_g, sB = e * bv_g;
        #pragma unroll
        for (int off = 32; off > 0; off >>= 1) {
            s  += __shfl_xor(s,  off);
            sA += __shfl_xor(sA, off);
            sB += __shfl_xor(sB, off);
        }
        const float inv = 1.f / s;
        const float woh = Wo[h];
        cA += woh * (sA * inv);
        cB += woh * (sB * inv);
    }
    if (lane == 0) { ldsA[wave] = cA; ldsB[wave] = cB; }
    __syncthreads();
    if (wave == 0) {
        float a = (lane < NWAVES) ? ldsA[lane] : 0.f;
        float c = (lane < NWAVES) ? ldsB[lane] : 0.f;
        #pragma unroll
        for (int off = 8; off > 0; off >>= 1) {
            a += __shfl_down(a, off);
            c += __shfl_down(c, off);
        }
        if (lane == 0) { sAlpha = a; sBeta = c + bo[0]; }
    }
    __syncthreads();
    const float alpha = sAlpha, beta = sBeta;

    // ---------------- Pass 2: this block writes its contiguous 1/CHUNKS ----
    const int i0 = (chunk * nvec) / CHUNKS;
    const int i1 = ((chunk + 1) * nvec) / CHUNKS;
    float4* yv = reinterpret_cast<float4*>(yb);
    for (int i = i0 + tid; i < i1; i += NTHREADS) {
        float4 v = xv[i];                 // L1/L2-hot: read in pass 1
        float4 r;
        r.x = fmaf(alpha, v.x, beta);
        r.y = fmaf(alpha, v.y, beta);
        r.z = fmaf(alpha, v.z, beta);
        r.w = fmaf(alpha, v.w, beta);
        yv[i] = r;
    }
    if (chunk == CHUNKS - 1) {
        for (int i = (nvec << 2) + tid; i < N; i += NTHREADS)
            yb[i] = fmaf(alpha, xb[i], beta);
    }
}

extern "C" void kernel_launch(void* const* d_in, const int* in_sizes, int n_in,
                              void* d_out, int out_size, void* d_ws, size_t ws_size,
                              hipStream_t stream) {
    const float* x  = (const float*)d_in[0];
    const float* Wq = (const float*)d_in[1];
    const float* bq = (const float*)d_in[2];
    const float* Wk = (const float*)d_in[3];
    const float* bk = (const float*)d_in[4];
    const float* Wv = (const float*)d_in[5];
    const float* bv = (const float*)d_in[6];
    const float* Wo = (const float*)d_in[7];
    const float* bo = (const float*)d_in[8];
    float* out = (float*)d_out;

    const int B = 64;
    const int N = in_sizes[0] / B;  // 86*86 = 7396

    spatial_attn_fused<<<B * CHUNKS, NTHREADS, 0, stream>>>(
        x, Wq, bq, Wk, bk, Wv, bv, Wo, bo, out, N);
}

// Round 4
// 12.565 us; speedup vs baseline: 1.3628x; 1.3628x over previous
//
#include <hip/hip_runtime.h>
#include <math.h>

#define HID 64
#define CHUNKS 4
#define NTHREADS 1024
#define NWAVES (NTHREADS / 64)

__global__ __launch_bounds__(NTHREADS) void spatial_attn_fused(
    const float* __restrict__ x,   // [B, N] flat
    const float* __restrict__ Wq, const float* __restrict__ bq,
    const float* __restrict__ Wk, const float* __restrict__ bk,
    const float* __restrict__ Wv, const float* __restrict__ bv,
    const float* __restrict__ Wo, const float* __restrict__ bo,
    float* __restrict__ out,       // [B, N] flat
    int N)
{
    // bid = b + 64*chunk  ->  the 4 blocks of one batch land on the same XCD
    // (64 % 8 == 0), so their redundant pass-1 reads share one L2.
    // 256 blocks = exactly 1 block/CU: all blocks co-resident in one round.
    const int bid   = blockIdx.x;
    const int b     = bid & 63;
    const int chunk = bid >> 6;
    const int tid   = threadIdx.x;
    const int wave  = tid >> 6, lane = tid & 63;
    const float* xb = x   + (size_t)b * N;
    float*       yb = out + (size_t)b * N;

    // ---------------- Pass 1 (redundant per chunk): S1 = Σx, S2 = Σx² ------
    float s1 = 0.f, s2 = 0.f;
    const int nvec = N >> 2;                       // 7396 -> 1849 float4s
    const float4* xv = reinterpret_cast<const float4*>(xb);
    for (int i = tid; i < nvec; i += NTHREADS) {
        float4 v = xv[i];
        s1 += (v.x + v.y) + (v.z + v.w);
        s2 += v.x * v.x + v.y * v.y + v.z * v.z + v.w * v.w;
    }
    for (int i = (nvec << 2) + tid; i < N; i += NTHREADS) {  // tail (none for 7396)
        float v = xb[i];
        s1 += v; s2 += v * v;
    }
    #pragma unroll
    for (int off = 32; off > 0; off >>= 1) {
        s1 += __shfl_down(s1, off);
        s2 += __shfl_down(s2, off);
    }
    __shared__ float lds1[NWAVES], lds2[NWAVES], ldsA[NWAVES], ldsB[NWAVES];
    __shared__ float sS1, sS2, sAlpha, sBeta;
    if (lane == 0) { lds1[wave] = s1; lds2[wave] = s2; }
    __syncthreads();
    if (wave == 0) {                       // parallel 16-entry reduce on wave 0
        float a = (lane < NWAVES) ? lds1[lane] : 0.f;
        float c = (lane < NWAVES) ? lds2[lane] : 0.f;
        #pragma unroll
        for (int off = 8; off > 0; off >>= 1) {
            a += __shfl_down(a, off);
            c += __shfl_down(c, off);
        }
        if (lane == 0) { sS1 = a; sS2 = c; }
    }
    __syncthreads();
    const float S1 = sS1, S2 = sS2;

    // ---------------- Softmax, wave-parallel: wave w owns heads 4w..4w+3 ---
    // sc[h][g] = P_h * wk_g + Q_h * bk_g   (rank-2 score matrix, C==1)
    const float scale = 0.125f;           // 1/sqrt(64)
    const float fN = (float)N;
    const float wk_g = Wk[lane], bk_g = bk[lane];
    const float wv_g = Wv[lane], bv_g = bv[lane];
    float cA = 0.f, cB = 0.f;
    #pragma unroll
    for (int j = 0; j < HID / NWAVES; ++j) {   // 4 heads per wave
        const int h = wave * (HID / NWAVES) + j;
        const float wqh = Wq[h], bqh = bq[h];  // wave-uniform loads
        const float P = (wqh * S2 + bqh * S1) * scale;
        const float Q = (wqh * S1 + bqh * fN) * scale;
        const float sc = P * wk_g + Q * bk_g;
        float m = sc;
        #pragma unroll
        for (int off = 32; off > 0; off >>= 1) m = fmaxf(m, __shfl_xor(m, off));
        const float e = __expf(sc - m);
        float s = e, sA = e * wv_g, sB = e * bv_g;
        #pragma unroll
        for (int off = 32; off > 0; off >>= 1) {
            s  += __shfl_xor(s,  off);
            sA += __shfl_xor(sA, off);
            sB += __shfl_xor(sB, off);
        }
        const float inv = 1.f / s;
        const float woh = Wo[h];
        cA += woh * (sA * inv);
        cB += woh * (sB * inv);
    }
    if (lane == 0) { ldsA[wave] = cA; ldsB[wave] = cB; }
    __syncthreads();
    if (wave == 0) {
        float a = (lane < NWAVES) ? ldsA[lane] : 0.f;
        float c = (lane < NWAVES) ? ldsB[lane] : 0.f;
        #pragma unroll
        for (int off = 8; off > 0; off >>= 1) {
            a += __shfl_down(a, off);
            c += __shfl_down(c, off);
        }
        if (lane == 0) { sAlpha = a; sBeta = c + bo[0]; }
    }
    __syncthreads();
    const float alpha = sAlpha, beta = sBeta;

    // ---------------- Pass 2: this block writes its contiguous quarter -----
    const int i0 = (chunk * nvec) / CHUNKS;
    const int i1 = ((chunk + 1) * nvec) / CHUNKS;
    float4* yv = reinterpret_cast<float4*>(yb);
    for (int i = i0 + tid; i < i1; i += NTHREADS) {
        float4 v = xv[i];                 // L1/L2-hot: read in pass 1
        float4 r;
        r.x = fmaf(alpha, v.x, beta);
        r.y = fmaf(alpha, v.y, beta);
        r.z = fmaf(alpha, v.z, beta);
        r.w = fmaf(alpha, v.w, beta);
        yv[i] = r;
    }
    if (chunk == CHUNKS - 1) {
        for (int i = (nvec << 2) + tid; i < N; i += NTHREADS)
            yb[i] = fmaf(alpha, xb[i], beta);
    }
}

extern "C" void kernel_launch(void* const* d_in, const int* in_sizes, int n_in,
                              void* d_out, int out_size, void* d_ws, size_t ws_size,
                              hipStream_t stream) {
    const float* x  = (const float*)d_in[0];
    const float* Wq = (const float*)d_in[1];
    const float* bq = (const float*)d_in[2];
    const float* Wk = (const float*)d_in[3];
    const float* bk = (const float*)d_in[4];
    const float* Wv = (const float*)d_in[5];
    const float* bv = (const float*)d_in[6];
    const float* Wo = (const float*)d_in[7];
    const float* bo = (const float*)d_in[8];
    float* out = (float*)d_out;

    const int B = 64;
    const int N = in_sizes[0] / B;  // 86*86 = 7396

    spatial_attn_fused<<<B * CHUNKS, NTHREADS, 0, stream>>>(
        x, Wq, bq, Wk, bk, Wv, bv, Wo, bo, out, N);
}